// Round 2
// baseline (7075.198 us; speedup 1.0000x reference)
//
#include <hip/hip_runtime.h>
#include <math.h>

#define NN 100000
#define NE 3200000
#define NC 20
#define ND 25
#define NG 1024
#define BN_EPS 1e-5f

__device__ __forceinline__ float sigmoidf_(float x){
    return 1.f/(1.f + __expf(-x));
}
__device__ __forceinline__ float softplusf_(float x){
    // matches jax.nn.softplus = logaddexp(x,0) stable form
    return fmaxf(x, 0.f) + log1pf(__expf(-fabsf(x)));
}

// nodeproj row layout per node (stride 80 floats):
//   [fd(20) | sd(20) | fs(20) | ss(20)]
// fd = x @ Wf[0:20] + bf   (dst part, bias folded in)
// sd = x @ Ws[0:20] + bs
// fs = x @ Wf[20:40]       (src part)
// ss = x @ Ws[20:40]
__global__ __launch_bounds__(256) void node_proj_kernel(
    const float* __restrict__ xin,
    const float* __restrict__ Wf, const float* __restrict__ bf,
    const float* __restrict__ Ws, const float* __restrict__ bs,
    float* __restrict__ nodeproj, float* __restrict__ hpre)
{
    __shared__ float sWf[40*NC];
    __shared__ float sWs[40*NC];
    __shared__ float sbf[NC], sbs[NC];
    int tid = threadIdx.x;
    for (int i = tid; i < 40*NC; i += 256){ sWf[i] = Wf[i]; sWs[i] = Ws[i]; }
    if (tid < NC){ sbf[tid] = bf[tid]; sbs[tid] = bs[tid]; }
    __syncthreads();
    int n = blockIdx.x*256 + tid;
    if (n >= NN) return;

    float xv[NC];
    const float4* xr = (const float4*)(xin + (size_t)n*NC);
    #pragma unroll
    for (int q = 0; q < 5; q++){
        float4 t = xr[q];
        xv[4*q+0]=t.x; xv[4*q+1]=t.y; xv[4*q+2]=t.z; xv[4*q+3]=t.w;
    }
    float fd[NC], sd[NC], fs[NC], ss[NC];
    #pragma unroll
    for (int c = 0; c < NC; c++){ fd[c]=sbf[c]; sd[c]=sbs[c]; fs[c]=0.f; ss[c]=0.f; }
    #pragma unroll
    for (int k = 0; k < NC; k++){
        float xk = xv[k];
        #pragma unroll
        for (int c = 0; c < NC; c++){
            fd[c] += xk * sWf[k*NC + c];
            fs[c] += xk * sWf[(NC+k)*NC + c];
            sd[c] += xk * sWs[k*NC + c];
            ss[c] += xk * sWs[(NC+k)*NC + c];
        }
    }
    float4* np4 = (float4*)(nodeproj + (size_t)n*80);
    float4* hp4 = (float4*)(hpre + (size_t)n*NC);
    #pragma unroll
    for (int q = 0; q < 5; q++){
        np4[q]      = make_float4(fd[4*q],fd[4*q+1],fd[4*q+2],fd[4*q+3]);
        np4[5+q]    = make_float4(sd[4*q],sd[4*q+1],sd[4*q+2],sd[4*q+3]);
        np4[10+q]   = make_float4(fs[4*q],fs[4*q+1],fs[4*q+2],fs[4*q+3]);
        np4[15+q]   = make_float4(ss[4*q],ss[4*q+1],ss[4*q+2],ss[4*q+3]);
        hp4[q]      = make_float4(xv[4*q],xv[4*q+1],xv[4*q+2],xv[4*q+3]);
    }
}

// One thread per edge. E = 3,200,000 = 12500 * 256 exactly.
__global__ __launch_bounds__(256) void edge_kernel(
    const float* __restrict__ eattr, const int* __restrict__ ei,
    const float* __restrict__ Wf, const float* __restrict__ Ws,
    const float* __restrict__ nodeproj, float* __restrict__ hpre)
{
    __shared__ float sWf[ND*NC];     // Wf rows 40..64 (edge-attr part)
    __shared__ float sWs[ND*NC];
    __shared__ float se[256*ND];     // staged edge_attr tile
    int tid = threadIdx.x;
    for (int i = tid; i < ND*NC; i += 256){ sWf[i] = Wf[40*NC + i]; sWs[i] = Ws[40*NC + i]; }
    size_t base = (size_t)blockIdx.x * 256;
    for (int i = tid; i < 256*ND; i += 256) se[i] = eattr[base*ND + i];
    __syncthreads();

    int eid = (int)base + tid;
    int srcn = ei[eid];
    int dstn = ei[NE + eid];

    const float4* npd = (const float4*)(nodeproj + (size_t)dstn*80);      // fd|sd
    const float4* nps = (const float4*)(nodeproj + (size_t)srcn*80 + 40); // fs|ss
    float dvals[40], svals[40];
    #pragma unroll
    for (int q = 0; q < 10; q++){
        float4 a = npd[q]; dvals[4*q]=a.x; dvals[4*q+1]=a.y; dvals[4*q+2]=a.z; dvals[4*q+3]=a.w;
        float4 b = nps[q]; svals[4*q]=b.x; svals[4*q+1]=b.y; svals[4*q+2]=b.z; svals[4*q+3]=b.w;
    }
    float e[ND];
    #pragma unroll
    for (int j = 0; j < ND; j++) e[j] = se[tid*ND + j];

    float* dsto = hpre + (size_t)dstn*NC;
    #pragma unroll
    for (int c = 0; c < NC; c++){
        float f = dvals[c]      + svals[c];       // fd + fs (bias folded into fd)
        float s = dvals[NC + c] + svals[NC + c];  // sd + ss
        #pragma unroll
        for (int j = 0; j < ND; j++){
            f += e[j] * sWf[j*NC + c];
            s += e[j] * sWs[j*NC + c];
        }
        float msg = sigmoidf_(f) * softplusf_(s);
        atomicAdd(dsto + c, msg);
    }
}

__global__ __launch_bounds__(256) void bn_stats_kernel(
    const float* __restrict__ hpre, float* __restrict__ stats)
{
    __shared__ float ssum[NC], ssq[NC];
    int tid = threadIdx.x;
    if (tid < NC){ ssum[tid] = 0.f; ssq[tid] = 0.f; }
    __syncthreads();
    const int total = NN*NC;
    for (int i = blockIdx.x*256 + tid; i < total; i += gridDim.x*256){
        float v = hpre[i];
        int c = i % NC;
        atomicAdd(&ssum[c], v);
        atomicAdd(&ssq[c], v*v);
    }
    __syncthreads();
    if (tid < NC){
        atomicAdd(&stats[tid], ssum[tid]);
        atomicAdd(&stats[NC + tid], ssq[tid]);
    }
}

__global__ void bn_finalize_kernel(float* __restrict__ stats,
    const float* __restrict__ gamma, const float* __restrict__ beta)
{
    int c = threadIdx.x;
    if (c < NC){
        float mu  = stats[c] / (float)NN;
        float var = stats[NC + c] / (float)NN - mu*mu;
        float scale = gamma[c] * rsqrtf(var + BN_EPS);
        stats[2*NC + c] = scale;
        stats[3*NC + c] = beta[c] - mu*scale;
    }
}

__global__ __launch_bounds__(256) void bn_apply_kernel(
    const float* __restrict__ hpre, const float* __restrict__ stats,
    float* __restrict__ h)
{
    int i = blockIdx.x*256 + threadIdx.x;
    if (i >= NN*NC) return;
    int c = i % NC;
    h[i] = hpre[i] * stats[2*NC + c] + stats[3*NC + c];
}

__device__ __forceinline__ int lower_bound_i(const int* __restrict__ a, int n, int v){
    int lo = 0, hi = n;
    while (lo < hi){ int mid = (lo + hi) >> 1; if (a[mid] < v) lo = mid + 1; else hi = mid; }
    return lo;
}

// one block per graph; batch is sorted so graph g occupies a contiguous range
__global__ __launch_bounds__(256) void pool_kernel(
    const float* __restrict__ h, const int* __restrict__ batch,
    float* __restrict__ pooled)
{
    __shared__ float acc[NC];
    __shared__ int sbound[2];
    int g = blockIdx.x;
    int tid = threadIdx.x;
    if (tid < NC) acc[tid] = 0.f;
    if (tid == 0){
        sbound[0] = lower_bound_i(batch, NN, g);
        sbound[1] = lower_bound_i(batch, NN, g + 1);
    }
    __syncthreads();
    int start = sbound[0], end = sbound[1];
    for (int i = start*NC + tid; i < end*NC; i += 256)
        atomicAdd(&acc[i % NC], h[i]);
    __syncthreads();
    if (tid < NC){
        float cnt = (float)(end - start);
        pooled[g*NC + tid] = acc[tid] / fmaxf(cnt, 1.f);
    }
}

__global__ __launch_bounds__(256) void head_kernel(
    const float* __restrict__ pooled,
    const float* __restrict__ W1, const float* __restrict__ c1,
    const float* __restrict__ W2, const float* __restrict__ c2,
    float* __restrict__ y)
{
    int g = blockIdx.x*256 + threadIdx.x;
    if (g >= NG) return;
    float p[NC], t[NC];
    #pragma unroll
    for (int c = 0; c < NC; c++) p[c] = pooled[g*NC + c];
    #pragma unroll
    for (int j = 0; j < NC; j++){
        float a = c1[j];
        #pragma unroll
        for (int k = 0; k < NC; k++) a += p[k] * W1[k*NC + j];
        t[j] = (a > 0.f) ? a : 0.01f * a;
    }
    #pragma unroll
    for (int j = 0; j < NC; j++){
        float a = c2[j];
        #pragma unroll
        for (int k = 0; k < NC; k++) a += t[k] * W2[k*NC + j];
        y[g*NC + j] = a;
    }
}

extern "C" void kernel_launch(void* const* d_in, const int* in_sizes, int n_in,
                              void* d_out, int out_size, void* d_ws, size_t ws_size,
                              hipStream_t stream)
{
    (void)in_sizes; (void)n_in; (void)out_size; (void)ws_size;
    const float* x    = (const float*)d_in[0];
    const int*   ei   = (const int*)d_in[1];
    const float* ea   = (const float*)d_in[2];
    const int*   batch= (const int*)d_in[3];
    const float* Wf0 = (const float*)d_in[4];
    const float* bf0 = (const float*)d_in[5];
    const float* Ws0 = (const float*)d_in[6];
    const float* bs0 = (const float*)d_in[7];
    const float* g0  = (const float*)d_in[8];
    const float* be0 = (const float*)d_in[9];
    const float* Wf1 = (const float*)d_in[10];
    const float* bf1 = (const float*)d_in[11];
    const float* Ws1 = (const float*)d_in[12];
    const float* bs1 = (const float*)d_in[13];
    const float* g1  = (const float*)d_in[14];
    const float* be1 = (const float*)d_in[15];
    const float* W1  = (const float*)d_in[16];
    const float* c1  = (const float*)d_in[17];
    const float* W2  = (const float*)d_in[18];
    const float* c2  = (const float*)d_in[19];
    float* out = (float*)d_out;

    char* ws = (char*)d_ws;
    float* nodeproj = (float*)(ws);                    // N*80*4  = 32,000,000 B
    float* hpre     = (float*)(ws + 32000000);         // N*20*4  =  8,000,000 B
    float* h        = (float*)(ws + 40000000);         // N*20*4  =  8,000,000 B
    float* stats    = (float*)(ws + 48000000);         // 80*4    = 320 B
    float* pooled   = (float*)(ws + 48000512);         // G*20*4  = 81,920 B

    const int nblk_node = (NN + 255)/256;    // 391
    const int nblk_edge = NE/256;            // 12500 (exact)
    const int nblk_app  = (NN*NC + 255)/256; // 7813

    // ---- layer 0 ----
    node_proj_kernel<<<nblk_node,256,0,stream>>>(x, Wf0, bf0, Ws0, bs0, nodeproj, hpre);
    edge_kernel<<<nblk_edge,256,0,stream>>>(ea, ei, Wf0, Ws0, nodeproj, hpre);
    hipMemsetAsync(stats, 0, 2*NC*sizeof(float), stream);
    bn_stats_kernel<<<1024,256,0,stream>>>(hpre, stats);
    bn_finalize_kernel<<<1,64,0,stream>>>(stats, g0, be0);
    bn_apply_kernel<<<nblk_app,256,0,stream>>>(hpre, stats, h);

    // ---- layer 1 ----
    node_proj_kernel<<<nblk_node,256,0,stream>>>(h, Wf1, bf1, Ws1, bs1, nodeproj, hpre);
    edge_kernel<<<nblk_edge,256,0,stream>>>(ea, ei, Wf1, Ws1, nodeproj, hpre);
    hipMemsetAsync(stats, 0, 2*NC*sizeof(float), stream);
    bn_stats_kernel<<<1024,256,0,stream>>>(hpre, stats);
    bn_finalize_kernel<<<1,64,0,stream>>>(stats, g1, be1);
    bn_apply_kernel<<<nblk_app,256,0,stream>>>(hpre, stats, h);

    // ---- pool + head ----
    pool_kernel<<<NG,256,0,stream>>>(h, batch, pooled);
    head_kernel<<<(NG+255)/256,256,0,stream>>>(pooled, W1, c1, W2, c2, out);
}